// Round 12
// baseline (95.403 us; speedup 1.0000x reference)
//
#include <hip/hip_runtime.h>

#define N_ATOMS 250000
#define NR 8
#define BLK 256          // threads per block == atoms per block
#define NP 36            // tril pairs
#define NBLK ((N_ATOMS + BLK - 1) / BLK)   // 977

typedef float f4 __attribute__((ext_vector_type(4)));

// R10 with ONE change: plain stores instead of __builtin_nontemporal_store.
// Rationale: R10's reads are 100% upfront (pure-write regime after ~15us,
// like the 6.9 TB/s fill), and writeout is single-owner 1KB full-line bursts
// -> test whether the plain-store/L2 path now matches the fill's bandwidth.
__global__ __launch_bounds__(BLK, 2) void moment_contr_kernel(
    const float* __restrict__ m1,   // [A, 8, 3]
    const float* __restrict__ m2,   // [A, 8, 3, 3]
    float* __restrict__ out)        // out[p*2000000 + t*250000 + a]
{
    __shared__ float sbuf[2][NP][BLK];   // 2 x 36 KB = 72 KB -> 2 blocks/CU

    // --- bijective XCD-chunked swizzle (977 % 8 != 0) ---
    const int orig = blockIdx.x;
    const int q = NBLK / 8, r = NBLK % 8;      // 122, 1
    const int xcd = orig & 7;
    const int wgid = (xcd < r ? xcd * (q + 1)
                              : r * (q + 1) + (xcd - r) * q) + (orig >> 3);

    const int tid  = threadIdx.x;
    const int wid  = tid >> 6;      // 0..3
    const int lane = tid & 63;
    const long long block_base = (long long)wgid * BLK;
    const long long a = block_base + tid;
    const bool live = (a < N_ATOMS);

    // ---- upfront read burst: m1 (6x f4) + full m2 (18x f4) ----
    float m1v[24];
    float m2v[72];
    if (live) {
        const f4* p1 = reinterpret_cast<const f4*>(m1 + (size_t)a * 24);
        const f4* p2 = reinterpret_cast<const f4*>(m2 + (size_t)a * 72);
        #pragma unroll
        for (int k = 0; k < 6; ++k) {
            f4 v = p1[k];
            m1v[4*k+0] = v.x; m1v[4*k+1] = v.y;
            m1v[4*k+2] = v.z; m1v[4*k+3] = v.w;
        }
        #pragma unroll
        for (int k = 0; k < 18; ++k) {
            f4 v = p2[k];
            m2v[4*k+0] = v.x; m2v[4*k+1] = v.y;
            m2v[4*k+2] = v.z; m2v[4*k+3] = v.w;
        }
    } else {
        #pragma unroll
        for (int k = 0; k < 24; ++k) m1v[k] = 0.f;
        #pragma unroll
        for (int k = 0; k < 72; ++k) m2v[k] = 0.f;
    }

    // ---- 8 t-passes: compute -> stage buf[t&1] -> raw barrier -> 1KB-run
    //      cooperative writeout. Double buffer => 1 barrier per pass.
    #pragma unroll
    for (int t = 0; t < NR; ++t) {
        // B[s][i] = sum_j m1[s,j] * m2[t,i,j]
        float B[24];
        #pragma unroll
        for (int s = 0; s < NR; ++s) {
            #pragma unroll
            for (int i = 0; i < 3; ++i) {
                B[s*3+i] = m1v[s*3+0] * m2v[t*9 + i*3 + 0]
                         + m1v[s*3+1] * m2v[t*9 + i*3 + 1]
                         + m1v[s*3+2] * m2v[t*9 + i*3 + 2];
            }
        }

        // contr[r,s,t] -> block LDS buf[t&1]; p = r*(r+1)/2 + s (tril order)
        #pragma unroll
        for (int rr = 0; rr < NR; ++rr) {
            #pragma unroll
            for (int s = 0; s <= rr; ++s) {
                const int p = rr*(rr+1)/2 + s;
                sbuf[t & 1][p][tid] = m1v[rr*3+0] * B[s*3+0]
                                    + m1v[rr*3+1] * B[s*3+1]
                                    + m1v[rr*3+2] * B[s*3+2];
            }
        }

        // own LDS writes complete, then rendezvous — raw barrier, NO vmcnt
        // drain (prior stores stay in flight).
        asm volatile("s_waitcnt lgkmcnt(0)\n\ts_barrier" ::: "memory");

        // ---- cooperative writeout: wave wid owns p = 9*wid .. 9*wid+8.
        // One ds_read_b128 + one plain dwordx4 per region: 1 KB contiguous
        // per instruction, single-owner per (p,t) region.
        #pragma unroll
        for (int k = 0; k < 9; ++k) {
            const int p = wid * 9 + k;
            const long long g = block_base + 4 * lane;
            if (g + 4 <= N_ATOMS) {   // N%4==0: exact f4 guard
                f4 v = *reinterpret_cast<const f4*>(&sbuf[t & 1][p][4 * lane]);
                *reinterpret_cast<f4*>(
                    out + (size_t)p * (NR * N_ATOMS)
                        + (size_t)t * N_ATOMS + g) = v;
            }
        }
    }
}

extern "C" void kernel_launch(void* const* d_in, const int* in_sizes, int n_in,
                              void* d_out, int out_size, void* d_ws, size_t ws_size,
                              hipStream_t stream) {
    const float* m1 = (const float*)d_in[0];
    const float* m2 = (const float*)d_in[1];
    float* out = (float*)d_out;

    hipLaunchKernelGGL(moment_contr_kernel, dim3(NBLK), dim3(BLK), 0, stream,
                       m1, m2, out);
}

// Round 13
// 68.184 us; speedup vs baseline: 1.3992x; 1.3992x over previous
//
#include <hip/hip_runtime.h>

#define N_ATOMS 250000
#define NR 8
#define BLK 256          // threads per block == atoms per block
#define NP 36            // tril pairs
#define NBLK ((N_ATOMS + BLK - 1) / BLK)   // 977

typedef float f4 __attribute__((ext_vector_type(4)));

// FINAL (= R10, best: 68.1 us, ~5.6 TB/s effective on 384 MB ideal traffic).
// Structure: upfront burst read (m1+m2, 24x dwordx4/lane) -> 8 t-passes of
// {compute -> stage into double-buffered block LDS -> raw lgkmcnt+s_barrier
// (no vmcnt drain) -> cooperative writeout}, each (p,t) region written by ONE
// wave as ONE 1 KB NT dwordx4 burst. XCD-chunked bijective block swizzle.
// Measured levers: NT stores +40% (R8/R12), stall/prefetch +24% (R5),
// granule aggregation +8.6% (R10), barrier-free +4% (R6), read phasing +2%
// (R7/R9); occupancy 2 vs 4 waves/SIMD null (R9).
__global__ __launch_bounds__(BLK, 2) void moment_contr_kernel(
    const float* __restrict__ m1,   // [A, 8, 3]
    const float* __restrict__ m2,   // [A, 8, 3, 3]
    float* __restrict__ out)        // out[p*2000000 + t*250000 + a]
{
    __shared__ float sbuf[2][NP][BLK];   // 2 x 36 KB = 72 KB -> 2 blocks/CU

    // --- bijective XCD-chunked swizzle (977 % 8 != 0) ---
    const int orig = blockIdx.x;
    const int q = NBLK / 8, r = NBLK % 8;      // 122, 1
    const int xcd = orig & 7;
    const int wgid = (xcd < r ? xcd * (q + 1)
                              : r * (q + 1) + (xcd - r) * q) + (orig >> 3);

    const int tid  = threadIdx.x;
    const int wid  = tid >> 6;      // 0..3
    const int lane = tid & 63;
    const long long block_base = (long long)wgid * BLK;
    const long long a = block_base + tid;
    const bool live = (a < N_ATOMS);

    // ---- upfront read burst: m1 (6x f4) + full m2 (18x f4) ----
    float m1v[24];
    float m2v[72];
    if (live) {
        const f4* p1 = reinterpret_cast<const f4*>(m1 + (size_t)a * 24);
        const f4* p2 = reinterpret_cast<const f4*>(m2 + (size_t)a * 72);
        #pragma unroll
        for (int k = 0; k < 6; ++k) {
            f4 v = p1[k];
            m1v[4*k+0] = v.x; m1v[4*k+1] = v.y;
            m1v[4*k+2] = v.z; m1v[4*k+3] = v.w;
        }
        #pragma unroll
        for (int k = 0; k < 18; ++k) {
            f4 v = p2[k];
            m2v[4*k+0] = v.x; m2v[4*k+1] = v.y;
            m2v[4*k+2] = v.z; m2v[4*k+3] = v.w;
        }
    } else {
        #pragma unroll
        for (int k = 0; k < 24; ++k) m1v[k] = 0.f;
        #pragma unroll
        for (int k = 0; k < 72; ++k) m2v[k] = 0.f;
    }

    // ---- 8 t-passes: compute -> stage buf[t&1] -> raw barrier -> 1KB-run
    //      cooperative NT writeout. Double buffer => 1 barrier per pass.
    //      (Read-completion of buf[i] at pass t is covered by the pass-t+1
    //      lgkmcnt(0) before barrier t+1, which precedes pass-t+2 writes.)
    #pragma unroll
    for (int t = 0; t < NR; ++t) {
        // B[s][i] = sum_j m1[s,j] * m2[t,i,j]
        float B[24];
        #pragma unroll
        for (int s = 0; s < NR; ++s) {
            #pragma unroll
            for (int i = 0; i < 3; ++i) {
                B[s*3+i] = m1v[s*3+0] * m2v[t*9 + i*3 + 0]
                         + m1v[s*3+1] * m2v[t*9 + i*3 + 1]
                         + m1v[s*3+2] * m2v[t*9 + i*3 + 2];
            }
        }

        // contr[r,s,t] -> block LDS buf[t&1]; p = r*(r+1)/2 + s (tril order).
        // stride-1 dword writes per wave: conflict-free.
        #pragma unroll
        for (int rr = 0; rr < NR; ++rr) {
            #pragma unroll
            for (int s = 0; s <= rr; ++s) {
                const int p = rr*(rr+1)/2 + s;
                sbuf[t & 1][p][tid] = m1v[rr*3+0] * B[s*3+0]
                                    + m1v[rr*3+1] * B[s*3+1]
                                    + m1v[rr*3+2] * B[s*3+2];
            }
        }

        // own LDS writes complete, then rendezvous — raw barrier, NO vmcnt
        // drain, so prior NT stores stay in flight across the barrier.
        asm volatile("s_waitcnt lgkmcnt(0)\n\ts_barrier" ::: "memory");

        // ---- cooperative writeout: wave wid owns p = 9*wid .. 9*wid+8.
        // One ds_read_b128 + one NT dwordx4 per region: 64 lanes x 16 B =
        // 1 KB contiguous per instruction, single-owner per (p,t) region.
        #pragma unroll
        for (int k = 0; k < 9; ++k) {
            const int p = wid * 9 + k;
            const long long g = block_base + 4 * lane;
            if (g + 4 <= N_ATOMS) {   // N%4==0: exact f4 guard
                f4 v = *reinterpret_cast<const f4*>(&sbuf[t & 1][p][4 * lane]);
                __builtin_nontemporal_store(
                    v, reinterpret_cast<f4*>(
                        out + (size_t)p * (NR * N_ATOMS)
                            + (size_t)t * N_ATOMS + g));
            }
        }
    }
}

extern "C" void kernel_launch(void* const* d_in, const int* in_sizes, int n_in,
                              void* d_out, int out_size, void* d_ws, size_t ws_size,
                              hipStream_t stream) {
    const float* m1 = (const float*)d_in[0];
    const float* m2 = (const float*)d_in[1];
    float* out = (float*)d_out;

    hipLaunchKernelGGL(moment_contr_kernel, dim3(NBLK), dim3(BLK), 0, stream,
                       m1, m2, out);
}